// Round 1
// baseline (4880.948 us; speedup 1.0000x reference)
//
#include <hip/hip_runtime.h>
#include <hip/hip_bf16.h>
#include <math.h>

#define BB 8
#define SS 2048
#define HH 256
#define NHH 4
#define DD 64
#define MROWS (BB*SS)   // 16384

// ---------------------------------------------------------------------------
// mixed = input + attr + pos   (float4 vectorized)
__global__ __launch_bounds__(256) void fuse_mixed(const float* __restrict__ inp,
    const float* __restrict__ attr, const float* __restrict__ pos,
    float* __restrict__ out, int n4) {
    int i = blockIdx.x * blockDim.x + threadIdx.x;
    if (i < n4) {
        float4 a = ((const float4*)inp)[i];
        float4 b = ((const float4*)attr)[i];
        float4 c = ((const float4*)pos)[i];
        ((float4*)out)[i] = make_float4(a.x+b.x+c.x, a.y+b.y+c.y,
                                        a.z+b.z+c.z, a.w+b.w+c.w);
    }
}

// ---------------------------------------------------------------------------
// C[M,256] = A[M,256] @ W[256,256] + bias   (fp32, 64x64 tile, 4x4/thread)
__global__ __launch_bounds__(256) void gemm_bias(const float* __restrict__ A,
    const float* __restrict__ W, const float* __restrict__ bias,
    float* __restrict__ C) {
    __shared__ float As[16][65];   // [k][m]
    __shared__ float Ws[16][65];   // [k][n]
    int tid = threadIdx.x;
    int bm = blockIdx.x * 64;
    int bn = blockIdx.y * 64;
    int tx = tid & 15;    // n sub-index
    int ty = tid >> 4;    // m sub-index (0..15)
    float acc[4][4] = {};
    for (int k0 = 0; k0 < HH; k0 += 16) {
        {   // A tile: 64 rows x 16 k
            int col = tid & 15;
            int row = tid >> 4;
            #pragma unroll
            for (int i = 0; i < 4; ++i)
                As[col][row + 16*i] = A[(size_t)(bm + row + 16*i)*HH + k0 + col];
        }
        {   // W tile: 16 k x 64 n
            int col = tid & 63;
            int row = tid >> 6;
            #pragma unroll
            for (int i = 0; i < 4; ++i)
                Ws[row + 4*i][col] = W[(size_t)(k0 + row + 4*i)*HH + bn + col];
        }
        __syncthreads();
        #pragma unroll
        for (int kk = 0; kk < 16; ++kk) {
            float a[4], w[4];
            #pragma unroll
            for (int i = 0; i < 4; ++i) a[i] = As[kk][ty + 16*i];
            #pragma unroll
            for (int j = 0; j < 4; ++j) w[j] = Ws[kk][tx + 16*j];
            #pragma unroll
            for (int i = 0; i < 4; ++i)
                #pragma unroll
                for (int j = 0; j < 4; ++j)
                    acc[i][j] += a[i] * w[j];
        }
        __syncthreads();
    }
    #pragma unroll
    for (int i = 0; i < 4; ++i) {
        int row = bm + ty + 16*i;
        #pragma unroll
        for (int j = 0; j < 4; ++j) {
            int col = bn + tx + 16*j;
            C[(size_t)row*HH + col] = acc[i][j] + bias[col];
        }
    }
}

// ---------------------------------------------------------------------------
// attention: one block (256 thr) per (b, h, qi).
// scores -> LDS, block softmax, PV with coalesced V reads.
__global__ __launch_bounds__(256) void attn(const float* __restrict__ Q,
    const float* __restrict__ K, const float* __restrict__ V,
    const float* __restrict__ mask, float* __restrict__ O) {
    __shared__ float sc[SS];       // scores / unnormalized probs (8KB)
    __shared__ float red[256];     // reductions + PV partials
    __shared__ float qs[DD];
    int qi = blockIdx.x, h = blockIdx.y, b = blockIdx.z;
    int tid = threadIdx.x;
    int lane = tid & 63, g = tid >> 6;

    const float* qrow = Q + ((size_t)(b*SS + qi)*HH + h*DD);
    if (tid < DD) qs[tid] = qrow[tid] * 0.125f;   // 1/sqrt(64)
    __syncthreads();

    const float* Kb   = K + ((size_t)b*SS*HH + h*DD);
    const float* Vb   = V + ((size_t)b*SS*HH + h*DD);
    const float* mrow = mask + ((size_t)b*SS + qi)*SS;

    // scores: each thread handles 8 keys
    for (int kj = tid; kj < SS; kj += 256) {
        const float4* kr = (const float4*)(Kb + (size_t)kj*HH);
        float acc = 0.f;
        #pragma unroll
        for (int d4 = 0; d4 < DD/4; ++d4) {
            float4 kv = kr[d4];
            acc += kv.x*qs[d4*4] + kv.y*qs[d4*4+1] + kv.z*qs[d4*4+2] + kv.w*qs[d4*4+3];
        }
        sc[kj] = acc + mrow[kj];
    }
    __syncthreads();

    // block max
    float lm = -1e30f;
    for (int kj = tid; kj < SS; kj += 256) lm = fmaxf(lm, sc[kj]);
    #pragma unroll
    for (int o = 32; o; o >>= 1) lm = fmaxf(lm, __shfl_xor(lm, o));
    if (!lane) red[g] = lm;
    __syncthreads();
    float m_all = fmaxf(fmaxf(red[0], red[1]), fmaxf(red[2], red[3]));

    // exp + block sum
    float lsum = 0.f;
    for (int kj = tid; kj < SS; kj += 256) {
        float e = __expf(sc[kj] - m_all);
        sc[kj] = e;
        lsum += e;
    }
    #pragma unroll
    for (int o = 32; o; o >>= 1) lsum += __shfl_xor(lsum, o);
    __syncthreads();                       // sc writes visible; red[0..3] reads done
    if (!lane) red[4 + g] = lsum;
    __syncthreads();
    float inv = 1.0f / (red[4] + red[5] + red[6] + red[7]);

    // PV: thread (d=lane, group=g), coalesced V reads
    float acc = 0.f;
    for (int i = 0; i < SS/4; ++i) {
        int kj = g*(SS/4) + i;
        acc += sc[kj] * Vb[(size_t)kj*HH + lane];
    }
    __syncthreads();                       // inv reads done before red reuse
    red[tid] = acc;
    __syncthreads();
    if (g == 0) {
        float r = (red[lane] + red[64+lane] + red[128+lane] + red[192+lane]) * inv;
        O[((size_t)(b*SS + qi))*HH + h*DD + lane] = r;
    }
}

// ---------------------------------------------------------------------------
// out = LayerNorm(hidden + input) * gamma + beta ; one block per row of 256
__global__ __launch_bounds__(256) void add_ln(const float* __restrict__ hidden,
    const float* __restrict__ inp, const float* __restrict__ gamma,
    const float* __restrict__ beta, float* __restrict__ out) {
    int row = blockIdx.x;
    int tid = threadIdx.x;
    int lane = tid & 63, wave = tid >> 6;
    __shared__ float red[8];
    float x = hidden[(size_t)row*HH + tid] + inp[(size_t)row*HH + tid];
    float s = x;
    #pragma unroll
    for (int o = 32; o; o >>= 1) s += __shfl_xor(s, o);
    if (!lane) red[wave] = s;
    __syncthreads();
    float mu = (red[0] + red[1] + red[2] + red[3]) * (1.0f/HH);
    float dx = x - mu;
    float v = dx * dx;
    #pragma unroll
    for (int o = 32; o; o >>= 1) v += __shfl_xor(v, o);
    if (!lane) red[4 + wave] = v;
    __syncthreads();
    float var = (red[4] + red[5] + red[6] + red[7]) * (1.0f/HH);
    out[(size_t)row*HH + tid] = dx * rsqrtf(var + 1e-12f) * gamma[tid] + beta[tid];
}

// ---------------------------------------------------------------------------
extern "C" void kernel_launch(void* const* d_in, const int* in_sizes, int n_in,
                              void* d_out, int out_size, void* d_ws, size_t ws_size,
                              hipStream_t stream) {
    const float* inp   = (const float*)d_in[0];
    const float* attr  = (const float*)d_in[1];
    const float* pos   = (const float*)d_in[2];
    const float* mask  = (const float*)d_in[3];
    const float* Wq    = (const float*)d_in[4];
    const float* bq    = (const float*)d_in[5];
    const float* Wk    = (const float*)d_in[6];
    const float* bk    = (const float*)d_in[7];
    const float* Wv    = (const float*)d_in[8];
    const float* bv    = (const float*)d_in[9];
    const float* Wd    = (const float*)d_in[10];
    const float* bd    = (const float*)d_in[11];
    const float* gamma = (const float*)d_in[12];
    const float* beta  = (const float*)d_in[13];
    float* out = (float*)d_out;

    const size_t NEL = (size_t)BB*SS*HH;   // 4,194,304
    float* mixed = (float*)d_ws;           // later: ctx
    float* q     = mixed + NEL;            // later: hidden
    float* k     = mixed + 2*NEL;
    float* v     = mixed + 3*NEL;

    fuse_mixed<<<(int)(NEL/4/256), 256, 0, stream>>>(inp, attr, pos, mixed, (int)(NEL/4));

    dim3 gg(MROWS/64, HH/64);   // (256, 4)
    gemm_bias<<<gg, 256, 0, stream>>>(mixed, Wq, bq, q);
    gemm_bias<<<gg, 256, 0, stream>>>(mixed, Wk, bk, k);
    gemm_bias<<<gg, 256, 0, stream>>>(inp,   Wv, bv, v);

    attn<<<dim3(SS, NHH, BB), 256, 0, stream>>>(q, k, v, mask, mixed);  // ctx -> mixed

    gemm_bias<<<gg, 256, 0, stream>>>(mixed, Wd, bd, q);                // hidden -> q

    add_ln<<<MROWS, 256, 0, stream>>>(q, inp, gamma, beta, out);
}

// Round 2
// 286.201 us; speedup vs baseline: 17.0543x; 17.0543x over previous
//
#include <hip/hip_runtime.h>
#include <hip/hip_bf16.h>
#include <math.h>

#define BB 8
#define SS 2048
#define HH 256
#define NHH 4
#define DD 64
#define MROWS (BB*SS)   // 16384

typedef unsigned short u16;
typedef unsigned int   u32;
typedef __attribute__((ext_vector_type(8))) short bf16x8;
typedef __attribute__((ext_vector_type(4))) float f32x4;
typedef __attribute__((ext_vector_type(8))) u16   u16x8;

__device__ inline u16 f2bf(float f) {
    union { float f; u32 u; } v; v.f = f;
    u32 r = v.u + 0x7fffu + ((v.u >> 16) & 1u);   // RNE
    return (u16)(r >> 16);
}

// ---------------------------------------------------------------------------
// mixed = input + attr + pos   (float4 vectorized)
__global__ __launch_bounds__(256) void fuse_mixed(const float* __restrict__ inp,
    const float* __restrict__ attr, const float* __restrict__ pos,
    float* __restrict__ out, int n4) {
    int i = blockIdx.x * blockDim.x + threadIdx.x;
    if (i < n4) {
        float4 a = ((const float4*)inp)[i];
        float4 b = ((const float4*)attr)[i];
        float4 c = ((const float4*)pos)[i];
        ((float4*)out)[i] = make_float4(a.x+b.x+c.x, a.y+b.y+c.y,
                                        a.z+b.z+c.z, a.w+b.w+c.w);
    }
}

// ---------------------------------------------------------------------------
// C[M,256] = A[M,256] @ W[256,256] + bias   (fp32, 64x64 tile, 4x4/thread)
__global__ __launch_bounds__(256) void gemm_bias(const float* __restrict__ A,
    const float* __restrict__ W, const float* __restrict__ bias,
    float* __restrict__ C) {
    __shared__ float As[16][65];
    __shared__ float Ws[16][65];
    int tid = threadIdx.x;
    int bm = blockIdx.x * 64;
    int bn = blockIdx.y * 64;
    int tx = tid & 15;
    int ty = tid >> 4;
    float acc[4][4] = {};
    for (int k0 = 0; k0 < HH; k0 += 16) {
        {
            int col = tid & 15;
            int row = tid >> 4;
            #pragma unroll
            for (int i = 0; i < 4; ++i)
                As[col][row + 16*i] = A[(size_t)(bm + row + 16*i)*HH + k0 + col];
        }
        {
            int col = tid & 63;
            int row = tid >> 6;
            #pragma unroll
            for (int i = 0; i < 4; ++i)
                Ws[row + 4*i][col] = W[(size_t)(k0 + row + 4*i)*HH + bn + col];
        }
        __syncthreads();
        #pragma unroll
        for (int kk = 0; kk < 16; ++kk) {
            float a[4], w[4];
            #pragma unroll
            for (int i = 0; i < 4; ++i) a[i] = As[kk][ty + 16*i];
            #pragma unroll
            for (int j = 0; j < 4; ++j) w[j] = Ws[kk][tx + 16*j];
            #pragma unroll
            for (int i = 0; i < 4; ++i)
                #pragma unroll
                for (int j = 0; j < 4; ++j)
                    acc[i][j] += a[i] * w[j];
        }
        __syncthreads();
    }
    #pragma unroll
    for (int i = 0; i < 4; ++i) {
        int row = bm + ty + 16*i;
        #pragma unroll
        for (int j = 0; j < 4; ++j) {
            int col = bn + tx + 16*j;
            C[(size_t)row*HH + col] = acc[i][j] + bias[col];
        }
    }
}

// ---------------------------------------------------------------------------
// fp32 -> bf16 elementwise (8/thread)
__global__ __launch_bounds__(256) void cast_bf16(const float* __restrict__ in,
    u16* __restrict__ out, int n8) {
    int i = blockIdx.x * 256 + threadIdx.x;
    if (i >= n8) return;
    const float4* p = (const float4*)(in + (size_t)i*8);
    float4 a = p[0], b = p[1];
    u16x8 o;
    o[0]=f2bf(a.x); o[1]=f2bf(a.y); o[2]=f2bf(a.z); o[3]=f2bf(a.w);
    o[4]=f2bf(b.x); o[5]=f2bf(b.y); o[6]=f2bf(b.z); o[7]=f2bf(b.w);
    *(u16x8*)(out + (size_t)i*8) = o;
}

// ---------------------------------------------------------------------------
// V [B,S,H] f32  ->  Vt [B,NH,D,S] bf16  (per-head transpose via LDS)
__global__ __launch_bounds__(256) void cast_vt(const float* __restrict__ V,
    u16* __restrict__ Vt) {
    __shared__ float T[64][65];
    int s0 = blockIdx.x * 64, h = blockIdx.y, b = blockIdx.z;
    int tid = threadIdx.x;
    {
        int r = tid >> 2, cq = tid & 3;
        const float* src = V + ((size_t)(b*SS + s0 + r))*HH + h*DD + cq*16;
        #pragma unroll
        for (int j = 0; j < 4; ++j) {
            float4 v = ((const float4*)src)[j];
            T[r][cq*16 + j*4 + 0] = v.x;
            T[r][cq*16 + j*4 + 1] = v.y;
            T[r][cq*16 + j*4 + 2] = v.z;
            T[r][cq*16 + j*4 + 3] = v.w;
        }
    }
    __syncthreads();
    {
        int d = tid >> 2, sc = tid & 3;
        u16x8 o0, o1;
        #pragma unroll
        for (int j = 0; j < 8; ++j) o0[j] = f2bf(T[sc*16 + j][d]);
        #pragma unroll
        for (int j = 0; j < 8; ++j) o1[j] = f2bf(T[sc*16 + 8 + j][d]);
        u16* dst = Vt + (((size_t)(b*NHH + h))*DD + d)*SS + s0 + sc*16;
        *(u16x8*)dst = o0;
        *((u16x8*)(dst + 8)) = o1;
    }
}

// ---------------------------------------------------------------------------
// Flash attention, bf16 MFMA 16x16x32, swapped-operand layout.
// Block: 512 thr (8 waves), Q-tile 128 (16 q/wave), K-tile 64.
__global__ __launch_bounds__(512) void attn_mfma(
    const u16* __restrict__ Qb,   // [B][S][H] bf16
    const u16* __restrict__ Kb,   // [B][S][H] bf16
    const u16* __restrict__ Vt,   // [B][NH][D][S] bf16
    const float* __restrict__ mask, // [B][1][S][S]
    float* __restrict__ O)        // [B][S][H] f32 (ctx)
{
    __shared__ u16 KT[2][64*64];   // [key][d] swizzled, 8KB each
    __shared__ u16 VTs[2][64*64];  // [d][k] swizzled
    __shared__ u16 PT[8][16*64];   // per-wave P^T->A staging [q][k] swizzled

    int tid = threadIdx.x;
    int w = tid >> 6, l = tid & 63;
    int lq = l & 15, g = l >> 4;
    int qb = blockIdx.x, h = blockIdx.y, b = blockIdx.z;
    int q = qb*128 + w*16 + lq;

    // Q B-frags (direct from global, 16B/lane): B[d][q], d = 32*df + 8g + j
    bf16x8 qf[2];
    {
        const u16* qp = Qb + ((size_t)(b*SS + q))*HH + h*DD + g*8;
        qf[0] = *(const bf16x8*)qp;
        qf[1] = *(const bf16x8*)(qp + 32);
    }

    // staging assignment: 512 chunks of 16B per tile; thread -> (row, chunk)
    int srow = tid >> 3;      // key (K) / d (V)
    int sch  = tid & 7;
    const u16* kgp = Kb + ((size_t)(b*SS + srow))*HH + h*DD + sch*8;
    const u16* vgp = Vt + (((size_t)(b*NHH + h))*DD + srow)*SS + sch*8;
    int sidx = srow*64 + ((sch ^ (srow & 7)))*8;   // swizzled LDS elem index

    const float* mrow = mask + ((size_t)b*SS + q)*SS + g*4;

    f32x4 ot[4];
    #pragma unroll
    for (int dt = 0; dt < 4; ++dt) ot[dt] = (f32x4){0.f,0.f,0.f,0.f};
    float m = -1e30f, lsum = 0.f;

    // prologue: stage tile 0
    u16x8 kr = *(const u16x8*)kgp;
    u16x8 vr = *(const u16x8*)vgp;
    f32x4 mra[4], mrb[4];
    #pragma unroll
    for (int kt = 0; kt < 4; ++kt) mra[kt] = *(const f32x4*)(mrow + kt*16);
    *(u16x8*)&KT[0][sidx]  = kr;
    *(u16x8*)&VTs[0][sidx] = vr;
    __syncthreads();

    for (int t = 0; t < SS/64; ++t) {
        int cur = t & 1;
        if (t < SS/64 - 1) {
            kr = *(const u16x8*)(kgp + (size_t)(t+1)*64*HH);
            vr = *(const u16x8*)(vgp + (t+1)*64);
            #pragma unroll
            for (int kt = 0; kt < 4; ++kt)
                mrb[kt] = *(const f32x4*)(mrow + (t+1)*64 + kt*16);
        }

        // S^T = K @ Q^T : C[key][q]
        f32x4 st[4];
        #pragma unroll
        for (int kt = 0; kt < 4; ++kt) {
            st[kt] = (f32x4){0.f,0.f,0.f,0.f};
            int key = kt*16 + lq;
            #pragma unroll
            for (int df = 0; df < 2; ++df) {
                int c = (4*df + g) ^ (key & 7);
                bf16x8 a = *(const bf16x8*)&KT[cur][key*64 + c*8];
                st[kt] = __builtin_amdgcn_mfma_f32_16x16x32_bf16(a, qf[df], st[kt], 0,0,0);
            }
        }

        // scores + mask, online softmax (per-lane q = lq, keys 16kt+4g+j)
        float p[4][4];
        float tm = -1e30f;
        #pragma unroll
        for (int kt = 0; kt < 4; ++kt)
            #pragma unroll
            for (int j = 0; j < 4; ++j) {
                float s = st[kt][j]*0.125f + mra[kt][j];
                p[kt][j] = s;
                tm = fmaxf(tm, s);
            }
        tm = fmaxf(tm, __shfl_xor(tm, 16));
        tm = fmaxf(tm, __shfl_xor(tm, 32));
        float mn = fmaxf(m, tm);
        float scale = __expf(m - mn);
        float rs = 0.f;
        #pragma unroll
        for (int kt = 0; kt < 4; ++kt)
            #pragma unroll
            for (int j = 0; j < 4; ++j) {
                float e = __expf(p[kt][j] - mn);
                p[kt][j] = e;
                rs += e;
            }
        rs += __shfl_xor(rs, 16);
        rs += __shfl_xor(rs, 32);
        lsum = lsum*scale + rs;
        m = mn;
        #pragma unroll
        for (int dt = 0; dt < 4; ++dt) {
            ot[dt][0] *= scale; ot[dt][1] *= scale;
            ot[dt][2] *= scale; ot[dt][3] *= scale;
        }

        // pack P -> per-wave LDS (bf16, swizzled)
        #pragma unroll
        for (int kt = 0; kt < 4; ++kt) {
            u32 w0 = (u32)f2bf(p[kt][0]) | ((u32)f2bf(p[kt][1]) << 16);
            u32 w1 = (u32)f2bf(p[kt][2]) | ((u32)f2bf(p[kt][3]) << 16);
            int koff = kt*16 + g*4;
            int c = (koff >> 3) ^ (lq & 7);
            int idx = lq*64 + c*8 + (koff & 7);
            *(u32*)&PT[w][idx]     = w0;
            *(u32*)&PT[w][idx + 2] = w1;
        }

        // PV: O^T = V^T @ P^T : C[d][q]
        bf16x8 pb[2];
        #pragma unroll
        for (int kt2 = 0; kt2 < 2; ++kt2) {
            int c = (4*kt2 + g) ^ (lq & 7);
            pb[kt2] = *(const bf16x8*)&PT[w][lq*64 + c*8];
        }
        #pragma unroll
        for (int dt = 0; dt < 4; ++dt) {
            int d = dt*16 + lq;
            #pragma unroll
            for (int kt2 = 0; kt2 < 2; ++kt2) {
                int c = (4*kt2 + g) ^ (d & 7);
                bf16x8 a = *(const bf16x8*)&VTs[cur][d*64 + c*8];
                ot[dt] = __builtin_amdgcn_mfma_f32_16x16x32_bf16(a, pb[kt2], ot[dt], 0,0,0);
            }
        }

        if (t < SS/64 - 1) {
            *(u16x8*)&KT[cur^1][sidx]  = kr;
            *(u16x8*)&VTs[cur^1][sidx] = vr;
            #pragma unroll
            for (int kt = 0; kt < 4; ++kt) mra[kt] = mrb[kt];
        }
        __syncthreads();
    }

    float inv = 1.0f / lsum;
    #pragma unroll
    for (int dt = 0; dt < 4; ++dt)
        #pragma unroll
        for (int j = 0; j < 4; ++j) {
            int d = dt*16 + g*4 + j;
            O[((size_t)(b*SS + q))*HH + h*DD + d] = ot[dt][j] * inv;
        }
}

// ---------------------------------------------------------------------------
// out = LayerNorm(hidden + input) * gamma + beta ; one block per row of 256
__global__ __launch_bounds__(256) void add_ln(const float* __restrict__ hidden,
    const float* __restrict__ inp, const float* __restrict__ gamma,
    const float* __restrict__ beta, float* __restrict__ out) {
    int row = blockIdx.x;
    int tid = threadIdx.x;
    int lane = tid & 63, wave = tid >> 6;
    __shared__ float red[8];
    float x = hidden[(size_t)row*HH + tid] + inp[(size_t)row*HH + tid];
    float s = x;
    #pragma unroll
    for (int o = 32; o; o >>= 1) s += __shfl_xor(s, o);
    if (!lane) red[wave] = s;
    __syncthreads();
    float mu = (red[0] + red[1] + red[2] + red[3]) * (1.0f/HH);
    float dx = x - mu;
    float v = dx * dx;
    #pragma unroll
    for (int o = 32; o; o >>= 1) v += __shfl_xor(v, o);
    if (!lane) red[4 + wave] = v;
    __syncthreads();
    float var = (red[4] + red[5] + red[6] + red[7]) * (1.0f/HH);
    out[(size_t)row*HH + tid] = dx * rsqrtf(var + 1e-12f) * gamma[tid] + beta[tid];
}

// ---------------------------------------------------------------------------
extern "C" void kernel_launch(void* const* d_in, const int* in_sizes, int n_in,
                              void* d_out, int out_size, void* d_ws, size_t ws_size,
                              hipStream_t stream) {
    const float* inp   = (const float*)d_in[0];
    const float* attr  = (const float*)d_in[1];
    const float* pos   = (const float*)d_in[2];
    const float* mask  = (const float*)d_in[3];
    const float* Wq    = (const float*)d_in[4];
    const float* bq    = (const float*)d_in[5];
    const float* Wk    = (const float*)d_in[6];
    const float* bk    = (const float*)d_in[7];
    const float* Wv    = (const float*)d_in[8];
    const float* bv    = (const float*)d_in[9];
    const float* Wd    = (const float*)d_in[10];
    const float* bd    = (const float*)d_in[11];
    const float* gamma = (const float*)d_in[12];
    const float* beta  = (const float*)d_in[13];
    float* out = (float*)d_out;

    const size_t NEL = (size_t)BB*SS*HH;   // 4,194,304
    float* A  = (float*)d_ws;      // mixed -> ctx
    float* Bw = A + NEL;           // qf -> vf -> hidden
    float* Cw = A + 2*NEL;         // kf -> Vt(bf16)
    u16*  Dq  = (u16*)(A + 3*NEL); // Q bf16 (8MB)
    u16*  Dk  = Dq + NEL;          // K bf16 (8MB)
    u16*  Vtb = (u16*)Cw;

    fuse_mixed<<<(int)(NEL/4/256), 256, 0, stream>>>(inp, attr, pos, A, (int)(NEL/4));

    dim3 gg(MROWS/64, HH/64);
    gemm_bias<<<gg, 256, 0, stream>>>(A, Wq, bq, Bw);
    gemm_bias<<<gg, 256, 0, stream>>>(A, Wk, bk, Cw);

    int n8 = (int)(NEL/8);
    cast_bf16<<<n8/256, 256, 0, stream>>>(Bw, Dq, n8);
    cast_bf16<<<n8/256, 256, 0, stream>>>(Cw, Dk, n8);

    gemm_bias<<<gg, 256, 0, stream>>>(inp, Wv, bv, Bw);          // vf
    cast_vt<<<dim3(SS/64, NHH, BB), 256, 0, stream>>>(Bw, Vtb);  // Vt bf16

    attn_mfma<<<dim3(SS/128, NHH, BB), 512, 0, stream>>>(Dq, Dk, Vtb, mask, A);

    gemm_bias<<<gg, 256, 0, stream>>>(A, Wd, bd, Bw);            // hidden

    add_ln<<<MROWS, 256, 0, stream>>>(Bw, inp, gamma, beta, out);
}

// Round 3
// 136.723 us; speedup vs baseline: 35.6994x; 2.0933x over previous
//
#include <hip/hip_runtime.h>
#include <hip/hip_bf16.h>
#include <math.h>

#define BB 8
#define SS 2048
#define HH 256
#define NHH 4
#define DD 64
#define MROWS (BB*SS)   // 16384

typedef unsigned short u16;
typedef unsigned int   u32;
typedef __attribute__((ext_vector_type(8))) short bf16x8;
typedef __attribute__((ext_vector_type(4))) float f32x4;
typedef __attribute__((ext_vector_type(8))) u16   u16x8;
typedef __attribute__((ext_vector_type(4))) u16   u16x4;

__device__ inline u16 f2bf(float f) {
    union { float f; u32 u; } v; v.f = f;
    u32 r = v.u + 0x7fffu + ((v.u >> 16) & 1u);   // RNE
    return (u16)(r >> 16);
}
__device__ inline float bf2f(u16 h) {
    union { u32 u; float f; } v; v.u = (u32)h << 16; return v.f;
}
__device__ inline void gload16(const u16* g, u16* l) {
    __builtin_amdgcn_global_load_lds(
        (const __attribute__((address_space(1))) u32*)g,
        (__attribute__((address_space(3))) u32*)l, 16, 0, 0);
}

// ---------------------------------------------------------------------------
// mixed = bf16(inp+attr+pos); inpb = bf16(inp)
__global__ __launch_bounds__(256) void fuse_mixed_cast(const float* __restrict__ inp,
    const float* __restrict__ attr, const float* __restrict__ pos,
    u16* __restrict__ mixed, u16* __restrict__ inpb, int n8) {
    int i = blockIdx.x * 256 + threadIdx.x;
    if (i >= n8) return;
    const f32x4* pi = (const f32x4*)(inp  + (size_t)i*8);
    const f32x4* pa = (const f32x4*)(attr + (size_t)i*8);
    const f32x4* pp = (const f32x4*)(pos  + (size_t)i*8);
    u16x8 om, oi;
    #pragma unroll
    for (int h = 0; h < 2; ++h) {
        f32x4 a = pi[h], b = pa[h], c = pp[h];
        #pragma unroll
        for (int j = 0; j < 4; ++j) {
            om[h*4+j] = f2bf(a[j] + b[j] + c[j]);
            oi[h*4+j] = f2bf(a[j]);
        }
    }
    *(u16x8*)(mixed + (size_t)i*8) = om;
    *(u16x8*)(inpb  + (size_t)i*8) = oi;
}

// ---------------------------------------------------------------------------
// Wt[y][n][k] = bf16(W_y[k][n])  (4 weights, 64x64 tiles via LDS)
__global__ __launch_bounds__(256) void transpose_w(const float* __restrict__ W0,
    const float* __restrict__ W1, const float* __restrict__ W2,
    const float* __restrict__ W3, u16* __restrict__ Wt) {
    const float* W = blockIdx.y==0 ? W0 : blockIdx.y==1 ? W1 : blockIdx.y==2 ? W2 : W3;
    u16* dst = Wt + (size_t)blockIdx.y*65536;
    int kt = blockIdx.x & 3, nt = blockIdx.x >> 2;
    __shared__ float T[64][65];
    int tid = threadIdx.x;
    int r = tid >> 2, cq = tid & 3;
    const float* src = W + (size_t)(kt*64 + r)*HH + nt*64 + cq*16;
    #pragma unroll
    for (int j = 0; j < 4; ++j) {
        f32x4 v = ((const f32x4*)src)[j];
        T[r][cq*16 + j*4 + 0] = v[0];
        T[r][cq*16 + j*4 + 1] = v[1];
        T[r][cq*16 + j*4 + 2] = v[2];
        T[r][cq*16 + j*4 + 3] = v[3];
    }
    __syncthreads();
    u16x8 o0, o1;
    #pragma unroll
    for (int j = 0; j < 8; ++j) o0[j] = f2bf(T[cq*16 + j][r]);
    #pragma unroll
    for (int j = 0; j < 8; ++j) o1[j] = f2bf(T[cq*16 + 8 + j][r]);
    u16* d = dst + (size_t)(nt*64 + r)*HH + kt*64 + cq*16;
    *(u16x8*)d       = o0;
    *(u16x8*)(d + 8) = o1;
}

// ---------------------------------------------------------------------------
// C[M,256] = A_bf16[M,256] @ W (Wt[n][k] bf16) + bias -> bf16 out
// 128x128 tile, BK=64, 4 waves, global_load_lds + XOR-swizzled LDS.
// VT=false: out[m][n] flat.  VT=true: out = Vt[b][h][d][s] per-head transpose.
template<bool VT>
__global__ __launch_bounds__(256) void gemm_mfma(
    const u16* __restrict__ A0, const u16* __restrict__ A1,
    const u16* __restrict__ Wt, const float* __restrict__ bias0,
    const float* __restrict__ bias1, u16* __restrict__ O0, u16* __restrict__ O1)
{
    __shared__ u16 As[2][128*64];
    __shared__ u16 Ws[2][128*64];
    int tid = threadIdx.x;
    int w = tid >> 6, l = tid & 63;
    int lq = l & 15, g4 = l >> 4;
    int w0 = w >> 1, w1 = w & 1;
    int z = blockIdx.z;
    const u16* A = z ? A1 : A0;
    const u16* Wz = Wt + (size_t)z*65536;
    const float* bias = z ? bias1 : bias0;
    u16* Oz = z ? O1 : O0;
    int bm = blockIdx.x*128, bn = blockIdx.y*128;

    // staging addresses: instr q covers rows (w*4+q)*8 + (l>>3), chunk c
    int rr0 = l >> 3;
    int cc0 = (l & 7) ^ (rr0 & 7);
    const u16* agp[4]; const u16* wgp[4];
    #pragma unroll
    for (int q = 0; q < 4; ++q) {
        int rr = (w*4+q)*8 + rr0;
        agp[q] = A  + (size_t)(bm + rr)*HH + cc0*8;
        wgp[q] = Wz + (size_t)(bn + rr)*HH + cc0*8;
    }

    f32x4 acc[4][4];
    #pragma unroll
    for (int i = 0; i < 4; ++i)
        #pragma unroll
        for (int j = 0; j < 4; ++j) acc[i][j] = (f32x4){0.f,0.f,0.f,0.f};

    #define STAGE(buf, k0) { \
        _Pragma("unroll") \
        for (int q = 0; q < 4; ++q) { \
            gload16(agp[q] + (k0), &As[buf][(w*4+q)*512]); \
            gload16(wgp[q] + (k0), &Ws[buf][(w*4+q)*512]); \
        } }

    STAGE(0, 0);
    __syncthreads();
    int cur = 0;
    #pragma unroll
    for (int t = 0; t < 4; ++t) {
        if (t < 3) STAGE(cur^1, (t+1)*64);
        #pragma unroll
        for (int kk = 0; kk < 2; ++kk) {
            bf16x8 af[4], wf[4];
            #pragma unroll
            for (int i = 0; i < 4; ++i) {
                int row = w0*64 + i*16 + lq;
                int cc = (kk*4 + g4) ^ (row & 7);
                af[i] = *(const bf16x8*)&As[cur][row*64 + cc*8];
            }
            #pragma unroll
            for (int j = 0; j < 4; ++j) {
                int row = w1*64 + j*16 + lq;
                int cc = (kk*4 + g4) ^ (row & 7);
                wf[j] = *(const bf16x8*)&Ws[cur][row*64 + cc*8];
            }
            #pragma unroll
            for (int i = 0; i < 4; ++i)
                #pragma unroll
                for (int j = 0; j < 4; ++j) {
                    if (VT)
                        acc[i][j] = __builtin_amdgcn_mfma_f32_16x16x32_bf16(af[i], wf[j], acc[i][j], 0,0,0);
                    else
                        acc[i][j] = __builtin_amdgcn_mfma_f32_16x16x32_bf16(wf[j], af[i], acc[i][j], 0,0,0);
                }
        }
        __syncthreads();
        cur ^= 1;
    }

    if (!VT) {
        // lane: fixed m = ..+lq ; 4 consecutive n per reg
        #pragma unroll
        for (int i = 0; i < 4; ++i) {
            size_t m = bm + w0*64 + i*16 + lq;
            #pragma unroll
            for (int j = 0; j < 4; ++j) {
                int n = bn + w1*64 + j*16 + g4*4;
                f32x4 bb = *(const f32x4*)&bias[n];
                u16x4 o;
                #pragma unroll
                for (int r = 0; r < 4; ++r) o[r] = f2bf(acc[i][j][r] + bb[r]);
                *(u16x4*)&Oz[m*HH + n] = o;
            }
        }
    } else {
        // lane: fixed n = ..+lq (-> h,d); 4 consecutive s per reg
        int b = bm >> 11;
        int sb = bm & 2047;
        #pragma unroll
        for (int i = 0; i < 4; ++i) {
            int s = sb + w0*64 + i*16 + g4*4;
            #pragma unroll
            for (int j = 0; j < 4; ++j) {
                int n = bn + w1*64 + j*16 + lq;
                float bs = bias[n];
                int h = n >> 6, d = n & 63;
                u16x4 o;
                #pragma unroll
                for (int r = 0; r < 4; ++r) o[r] = f2bf(acc[i][j][r] + bs);
                *(u16x4*)&Oz[(((size_t)b*NHH + h)*DD + d)*SS + s] = o;
            }
        }
    }
    #undef STAGE
}

// ---------------------------------------------------------------------------
// Flash attention, bf16 MFMA 16x16x32, swapped-operand layout. ctx out bf16.
__global__ __launch_bounds__(512) void attn_mfma(
    const u16* __restrict__ Qb, const u16* __restrict__ Kb,
    const u16* __restrict__ Vt, const float* __restrict__ mask,
    u16* __restrict__ O)
{
    __shared__ u16 KT[2][64*64];
    __shared__ u16 VTs[2][64*64];
    __shared__ u16 PT[8][16*64];

    int tid = threadIdx.x;
    int w = tid >> 6, l = tid & 63;
    int lq = l & 15, g = l >> 4;
    int qb = blockIdx.x, h = blockIdx.y, b = blockIdx.z;
    int q = qb*128 + w*16 + lq;

    bf16x8 qf[2];
    {
        const u16* qp = Qb + ((size_t)(b*SS + q))*HH + h*DD + g*8;
        qf[0] = *(const bf16x8*)qp;
        qf[1] = *(const bf16x8*)(qp + 32);
    }

    int srow = tid >> 3;
    int sch  = tid & 7;
    const u16* kgp = Kb + ((size_t)(b*SS + srow))*HH + h*DD + sch*8;
    const u16* vgp = Vt + (((size_t)(b*NHH + h))*DD + srow)*SS + sch*8;
    int sidx = srow*64 + ((sch ^ (srow & 7)))*8;

    const float* mrow = mask + ((size_t)b*SS + q)*SS + g*4;

    f32x4 ot[4];
    #pragma unroll
    for (int dt = 0; dt < 4; ++dt) ot[dt] = (f32x4){0.f,0.f,0.f,0.f};
    float m = -1e30f, lsum = 0.f;

    u16x8 kr = *(const u16x8*)kgp;
    u16x8 vr = *(const u16x8*)vgp;
    f32x4 mra[4], mrb[4];
    #pragma unroll
    for (int kt = 0; kt < 4; ++kt) mra[kt] = *(const f32x4*)(mrow + kt*16);
    *(u16x8*)&KT[0][sidx]  = kr;
    *(u16x8*)&VTs[0][sidx] = vr;
    __syncthreads();

    for (int t = 0; t < SS/64; ++t) {
        int cur = t & 1;
        if (t < SS/64 - 1) {
            kr = *(const u16x8*)(kgp + (size_t)(t+1)*64*HH);
            vr = *(const u16x8*)(vgp + (t+1)*64);
            #pragma unroll
            for (int kt = 0; kt < 4; ++kt)
                mrb[kt] = *(const f32x4*)(mrow + (t+1)*64 + kt*16);
        }

        f32x4 st[4];
        #pragma unroll
        for (int kt = 0; kt < 4; ++kt) {
            st[kt] = (f32x4){0.f,0.f,0.f,0.f};
            int key = kt*16 + lq;
            #pragma unroll
            for (int df = 0; df < 2; ++df) {
                int c = (4*df + g) ^ (key & 7);
                bf16x8 a = *(const bf16x8*)&KT[cur][key*64 + c*8];
                st[kt] = __builtin_amdgcn_mfma_f32_16x16x32_bf16(a, qf[df], st[kt], 0,0,0);
            }
        }

        float p[4][4];
        float tm = -1e30f;
        #pragma unroll
        for (int kt = 0; kt < 4; ++kt)
            #pragma unroll
            for (int j = 0; j < 4; ++j) {
                float s = st[kt][j]*0.125f + mra[kt][j];
                p[kt][j] = s;
                tm = fmaxf(tm, s);
            }
        tm = fmaxf(tm, __shfl_xor(tm, 16));
        tm = fmaxf(tm, __shfl_xor(tm, 32));
        float mn = fmaxf(m, tm);
        float scale = __expf(m - mn);
        float rs = 0.f;
        #pragma unroll
        for (int kt = 0; kt < 4; ++kt)
            #pragma unroll
            for (int j = 0; j < 4; ++j) {
                float e = __expf(p[kt][j] - mn);
                p[kt][j] = e;
                rs += e;
            }
        rs += __shfl_xor(rs, 16);
        rs += __shfl_xor(rs, 32);
        lsum = lsum*scale + rs;
        m = mn;
        #pragma unroll
        for (int dt = 0; dt < 4; ++dt) {
            ot[dt][0] *= scale; ot[dt][1] *= scale;
            ot[dt][2] *= scale; ot[dt][3] *= scale;
        }

        // pack P -> per-wave LDS (single 8B write per fragment)
        #pragma unroll
        for (int kt = 0; kt < 4; ++kt) {
            u16x4 pk;
            pk[0] = f2bf(p[kt][0]); pk[1] = f2bf(p[kt][1]);
            pk[2] = f2bf(p[kt][2]); pk[3] = f2bf(p[kt][3]);
            int koff = kt*16 + g*4;
            int c = (koff >> 3) ^ (lq & 7);
            int idx = lq*64 + c*8 + (koff & 7);
            *(u16x4*)&PT[w][idx] = pk;
        }

        bf16x8 pb[2];
        #pragma unroll
        for (int kt2 = 0; kt2 < 2; ++kt2) {
            int c = (4*kt2 + g) ^ (lq & 7);
            pb[kt2] = *(const bf16x8*)&PT[w][lq*64 + c*8];
        }
        #pragma unroll
        for (int dt = 0; dt < 4; ++dt) {
            int d = dt*16 + lq;
            #pragma unroll
            for (int kt2 = 0; kt2 < 2; ++kt2) {
                int c = (4*kt2 + g) ^ (d & 7);
                bf16x8 a = *(const bf16x8*)&VTs[cur][d*64 + c*8];
                ot[dt] = __builtin_amdgcn_mfma_f32_16x16x32_bf16(a, pb[kt2], ot[dt], 0,0,0);
            }
        }

        if (t < SS/64 - 1) {
            *(u16x8*)&KT[cur^1][sidx]  = kr;
            *(u16x8*)&VTs[cur^1][sidx] = vr;
            #pragma unroll
            for (int kt = 0; kt < 4; ++kt) mra[kt] = mrb[kt];
        }
        __syncthreads();
    }

    float inv = 1.0f / lsum;
    #pragma unroll
    for (int dt = 0; dt < 4; ++dt) {
        u16x4 o;
        #pragma unroll
        for (int j = 0; j < 4; ++j) o[j] = f2bf(ot[dt][j] * inv);
        *(u16x4*)&O[((size_t)(b*SS + q))*HH + h*DD + dt*16 + g*4] = o;
    }
}

// ---------------------------------------------------------------------------
// out = LayerNorm(bf16 hidden + input) * gamma + beta
__global__ __launch_bounds__(256) void add_ln(const u16* __restrict__ hidden,
    const float* __restrict__ inp, const float* __restrict__ gamma,
    const float* __restrict__ beta, float* __restrict__ out) {
    int row = blockIdx.x;
    int tid = threadIdx.x;
    int lane = tid & 63, wave = tid >> 6;
    __shared__ float red[8];
    float x = bf2f(hidden[(size_t)row*HH + tid]) + inp[(size_t)row*HH + tid];
    float s = x;
    #pragma unroll
    for (int o = 32; o; o >>= 1) s += __shfl_xor(s, o);
    if (!lane) red[wave] = s;
    __syncthreads();
    float mu = (red[0] + red[1] + red[2] + red[3]) * (1.0f/HH);
    float dx = x - mu;
    float v = dx * dx;
    #pragma unroll
    for (int o = 32; o; o >>= 1) v += __shfl_xor(v, o);
    if (!lane) red[4 + wave] = v;
    __syncthreads();
    float var = (red[4] + red[5] + red[6] + red[7]) * (1.0f/HH);
    out[(size_t)row*HH + tid] = dx * rsqrtf(var + 1e-12f) * gamma[tid] + beta[tid];
}

// ---------------------------------------------------------------------------
extern "C" void kernel_launch(void* const* d_in, const int* in_sizes, int n_in,
                              void* d_out, int out_size, void* d_ws, size_t ws_size,
                              hipStream_t stream) {
    const float* inp   = (const float*)d_in[0];
    const float* attr  = (const float*)d_in[1];
    const float* pos   = (const float*)d_in[2];
    const float* mask  = (const float*)d_in[3];
    const float* Wq    = (const float*)d_in[4];
    const float* bq    = (const float*)d_in[5];
    const float* Wk    = (const float*)d_in[6];
    const float* bk    = (const float*)d_in[7];
    const float* Wv    = (const float*)d_in[8];
    const float* bv    = (const float*)d_in[9];
    const float* Wd    = (const float*)d_in[10];
    const float* bd    = (const float*)d_in[11];
    const float* gamma = (const float*)d_in[12];
    const float* beta  = (const float*)d_in[13];
    float* out = (float*)d_out;

    const size_t NEL = (size_t)BB*SS*HH;   // 4,194,304
    u16* mixed = (u16*)d_ws;
    u16* inpb  = mixed + NEL;
    u16* Qb    = mixed + 2*NEL;
    u16* Kb    = mixed + 3*NEL;
    u16* Vtb   = mixed + 4*NEL;
    u16* ctx   = mixed + 5*NEL;
    u16* hid   = mixed + 6*NEL;
    u16* Wt    = mixed + 7*NEL;   // 4 x 65536 bf16

    fuse_mixed_cast<<<(int)(NEL/8/256), 256, 0, stream>>>(inp, attr, pos, mixed, inpb, (int)(NEL/8));
    transpose_w<<<dim3(16,4), 256, 0, stream>>>(Wq, Wk, Wv, Wd, Wt);

    gemm_mfma<false><<<dim3(128,2,2), 256, 0, stream>>>(mixed, mixed, Wt, bq, bk, Qb, Kb);
    gemm_mfma<true ><<<dim3(128,2,1), 256, 0, stream>>>(inpb, inpb, Wt + 2*65536, bv, bv, Vtb, Vtb);

    attn_mfma<<<dim3(SS/128, NHH, BB), 512, 0, stream>>>(Qb, Kb, Vtb, mask, ctx);

    gemm_mfma<false><<<dim3(128,2,1), 256, 0, stream>>>(ctx, ctx, Wt + 3*65536, bd, bd, hid, hid);

    add_ln<<<MROWS, 256, 0, stream>>>(hid, inp, gamma, beta, out);
}